// Round 1
// 78.744 us; speedup vs baseline: 1.0073x; 1.0073x over previous
//
#include <hip/hip_runtime.h>

// PatchMatch stereo — MI355X (gfx950), R15: 2 stream-ordered kernels.
// Lessons: grid.sync() ~60-100us on 8 XCDs -> plain launches (R8); noise-
// independent dots hoisted into banded cost volume via f16 MFMA (R8);
// per-(px,s) 8-half window depends only on (imin,sc) -> windows precomputed
// to wbuf (R12); MFMA operands swapped so epilogue is 6 ds_write_b64 (R14).
// R15: rounds 0..3 FUSED into one tiled kernel. Dep chain per round is only
// +-1 px, so a 16x16 output tile needs just a 20x18 round-0 halo: r0 on
// 20x18 (noise from global), r1 on 18x18, r2 on 18x16, r3 on 16x16, all
// through LDS with 3 barriers. Kills pm_part x2 launches + nbuf0/nbuf1
// round-trips; k1 drops its round-0 epilogue (pure window builder).
//   1) pm_build: CV band -> sCVx(LDS) -> windows -> wbuf
//   2) pm_prop:  r0,r1,r2,r3 per 16x16 tile (halo recompute, +20% evals)

namespace {
constexpr int C = 32;
constexpr int H = 128;
constexpr int W = 256;
constexpr int S = 12;
constexpr int HW = H * W;
constexpr int KD = 80;                // band width; k = xr - px + KOFF
constexpr int KOFF = 76;
constexpr int RT = 144;               // staged xr values per build block
constexpr int CMP = 148;              // cm pitch (dwords): 16B-aligned stores
constexpr int XP  = 148;              // sCVx pitch (halves): rows 8B-aligned
constexpr float TEMP_OVER_C = 7.0f / 32.0f;
constexpr float INTERVAL = 1.0f / (S + 1);

// fused propagation tile geometry
constexpr int HT = 16, WT = 16;
constexpr int R0R = HT + 4, R0C = WT + 2;   // 20 x 18 (round-0 halo)
constexpr int R1R = HT + 2, R1C = WT + 2;   // 18 x 18
constexpr int R2R = HT + 2, R2C = WT;       // 18 x 16

typedef _Float16 v2h __attribute__((ext_vector_type(2)));
typedef _Float16 v8h __attribute__((ext_vector_type(8)));
typedef float    v4f __attribute__((ext_vector_type(4)));
}

// ---- window position for (imin, sc): 8 halves [kb0 .. kb0+7] covers all taps
__device__ __forceinline__ int win_base(float imin, float sc) {
    int kb0 = ((int)floorf(-imin - sc) + KOFF) & ~1;   // even
    return kb0 < 0 ? 0 : (kb0 > KD - 8 ? KD - 8 : kb0);
}

// ---- eval from an 8-half register window ---------------------------------
__device__ __forceinline__ void eval_w(
    unsigned int u0, unsigned int u1, unsigned int u2, unsigned int u3,
    int kb0, int w, float imin, float sc, const float np[3],
    float& ds_out, float& dn_out)
{
    const unsigned long long lo = u0 | ((unsigned long long)u1 << 32); // h0..3
    const unsigned long long hi = u2 | ((unsigned long long)u3 << 32); // h4..7
    float dsamp[3], cost[3];
    #pragma unroll
    for (int c = 0; c < 3; ++c) {
        const float disp = fmaf(np[c], sc, imin);
        dsamp[c] = disp;
        const float xs = (float)w - disp;
        const float x0f = floorf(xs);
        const float fr = xs - x0f;
        int idx = ((int)x0f - w + KOFF) - kb0;     // in [0,6] by construction
        idx = idx < 0 ? 0 : (idx > 6 ? 6 : idx);
        unsigned int pair;
        if (idx < 3)       pair = (unsigned int)(lo >> (16 * idx));
        else if (idx == 3) pair = (unsigned int)((lo >> 48) | ((unsigned long long)u2 << 16));
        else               pair = (unsigned int)(hi >> (16 * (idx - 4)));
        const v2h ph = __builtin_bit_cast(v2h, pair);
        cost[c] = ((1.0f - fr) * (float)ph.x + fr * (float)ph.y) * TEMP_OVER_C;
    }
    const float m = fmaxf(cost[0], fmaxf(cost[1], cost[2]));
    const float e0 = __expf(cost[0] - m);
    const float e1 = __expf(cost[1] - m);
    const float e2 = __expf(cost[2] - m);
    const float inv = 1.0f / (e0 + e1 + e2);
    ds_out = (e0 * dsamp[0] + e1 * dsamp[1] + e2 * dsamp[2]) * inv;
    dn_out = (e0 * np[0] + e1 * np[1] + e2 * np[2]) * inv;
}

// ---------------- kernel 1: CV build (MFMA) + window export ---------------
// grid (H, 4), block 256 = 4 waves; block covers 64 px (w0B = 64*blockIdx.y).
__global__ __launch_bounds__(256, 2) void pm_build(
    const float* __restrict__ left, const float* __restrict__ right,
    const float* __restrict__ min_disp, const float* __restrict__ max_disp,
    uint4* __restrict__ wbuf)
{
    __shared__ unsigned int cm[16 * CMP];   // [c2][xo] f16-pair dwords, 9.5 KB
    __shared__ unsigned int rt[RT * 16];    // [xo][c2] transposed,       9.2 KB
    __shared__ _Float16 sCVx[64 * XP];      // [local px][xo], xr-major, 18.9 KB

    const int tid  = threadIdx.x;
    const int lane = tid & 63, wid = tid >> 6;
    const int q = lane >> 4, n = lane & 15;
    const int h = blockIdx.x, row = h * W;      // h fastest -> XCD locality
    const int w0B = 64 * blockIdx.y;
    const int w0w = w0B + 16 * wid;

    // pass A (vectorized): float4 groups -> cm[c2][xo]; xr = w0B - KOFF + xo
    #pragma unroll
    for (int j = 0; j < 3; ++j) {
        const int idx = tid + 256 * j;          // 0..767
        const int c2 = idx / 48;
        const int xg = idx - 48 * c2;
        if (xg < 36) {
            const int x0 = w0B - KOFF + 4 * xg;
            float4 a = {0.f, 0.f, 0.f, 0.f}, b = {0.f, 0.f, 0.f, 0.f};
            if (x0 >= 0 && x0 <= W - 4) {       // interior: unmasked float4
                a = *(const float4*)&right[(2 * c2)     * HW + row + x0];
                b = *(const float4*)&right[(2 * c2 + 1) * HW + row + x0];
            } else if (x0 >= -3 && x0 <= W - 1) {   // edge: element-masked
                float ae[4] = {0, 0, 0, 0}, be[4] = {0, 0, 0, 0};
                #pragma unroll
                for (int e = 0; e < 4; ++e) {
                    const int x = x0 + e;
                    if ((unsigned)x < (unsigned)W) {
                        ae[e] = right[(2 * c2)     * HW + row + x];
                        be[e] = right[(2 * c2 + 1) * HW + row + x];
                    }
                }
                a = make_float4(ae[0], ae[1], ae[2], ae[3]);
                b = make_float4(be[0], be[1], be[2], be[3]);
            }
            const v2h h0 = {(_Float16)a.x, (_Float16)b.x};
            const v2h h1 = {(_Float16)a.y, (_Float16)b.y};
            const v2h h2 = {(_Float16)a.z, (_Float16)b.z};
            const v2h h3 = {(_Float16)a.w, (_Float16)b.w};
            uint4 pk;
            pk.x = __builtin_bit_cast(unsigned int, h0);
            pk.y = __builtin_bit_cast(unsigned int, h1);
            pk.z = __builtin_bit_cast(unsigned int, h2);
            pk.w = __builtin_bit_cast(unsigned int, h3);
            *(uint4*)&cm[c2 * CMP + 4 * xg] = pk;   // 16B aligned
        }
    }
    __syncthreads();
    // pass B: transpose -> rt[xo][c2]
    #pragma unroll
    for (int i = 0; i < 9; ++i) {
        const int idx = tid + 256 * i;              // 16*144 = 2304 dwords
        const int c2 = idx & 15;
        const int xo = idx >> 4;
        rt[xo * 16 + c2] = cm[c2 * CMP + xo];
    }

    // B fragment (L): lane holds L[ch = q*8+j][px = w0w + n]
    v8h bL;
    #pragma unroll
    for (int j = 0; j < 8; ++j)
        bL[j] = (_Float16)left[(q * 8 + j) * HW + row + w0w + n];

    __syncthreads();

    const int pxl = 16 * wid + n;               // local px of this lane
    #pragma unroll
    for (int t = 0; t < 6; ++t) {
        // A fragment (R): lane holds R[ch = q*8+j][xo = 16*(wid+t) + n]
        const uint4 araw = *(const uint4*)&rt[(16 * (wid + t) + n) * 16 + q * 4];
        const v8h aR = __builtin_bit_cast(v8h, araw);
        v4f d = {0.f, 0.f, 0.f, 0.f};
        d = __builtin_amdgcn_mfma_f32_16x16x32_f16(aR, bL, d, 0, 0, 0);
        // D[m = xo-local][n = px-local]: lane holds 4 consecutive xo
        const v2h p01 = {(_Float16)d[0], (_Float16)d[1]};
        const v2h p23 = {(_Float16)d[2], (_Float16)d[3]};
        uint2 pk;
        pk.x = __builtin_bit_cast(unsigned int, p01);
        pk.y = __builtin_bit_cast(unsigned int, p23);
        const int xo = 16 * (wid + t) + 4 * q;      // multiple of 4 -> 8B aligned
        *(uint2*)&sCVx[pxl * XP + xo] = pk;         // one ds_write_b64
    }
    __syncthreads();

    // ---- window export only (round 0 moved to pm_prop), 64 px x 12 s ----
    const int px = tid & 63;                    // local pixel
    const int sq = tid >> 6;                    // 0..3
    const int wpx = w0B + px;
    const float mind = fmaxf(min_disp[row + wpx], 0.0f);
    const float maxd = fmaxf(max_disp[row + wpx], 0.0f);
    const float sc = (maxd - mind) * INTERVAL;
    const _Float16* rowp = &sCVx[px * XP];

    #pragma unroll
    for (int si = 0; si < 3; ++si) {
        const int s = 3 * sq + si;
        const float imin = fmaf(sc, (float)(s + 1), mind);
        const int kb0 = win_base(imin, sc);
        const int xo0 = kb0 + px;               // k = xo - px
        // 5 aligned dwords + funnel shift if odd start
        const unsigned int* cb = (const unsigned int*)&rowp[xo0 & ~1];
        const unsigned int v0 = cb[0], v1 = cb[1], v2 = cb[2], v3 = cb[3], v4 = cb[4];
        unsigned int u0, u1, u2, u3;
        if (xo0 & 1) {
            u0 = (v0 >> 16) | (v1 << 16);
            u1 = (v1 >> 16) | (v2 << 16);
            u2 = (v2 >> 16) | (v3 << 16);
            u3 = (v3 >> 16) | (v4 << 16);
        } else {
            u0 = v0; u1 = v1; u2 = v2; u3 = v3;
        }
        wbuf[s * HW + row + wpx] = make_uint4(u0, u1, u2, u3);  // coalesced 16B
    }
}

// ---------------- kernel 2: fused rounds 0..3 per 16x16 tile --------------
// grid (H/16, W/16, S), block 256. Halo recompute: r0 on 20x18 (noise from
// global, horizontal), r1 on 18x18 (vertical), r2 on 18x16 (horizontal),
// r3 on 16x16 (vertical) -> ds -> out. Windows + (imin,sc) staged once.
__global__ __launch_bounds__(256, 4) void pm_prop(
    const float* __restrict__ min_disp, const float* __restrict__ max_disp,
    const uint4* __restrict__ wbuf, const float* __restrict__ noise,
    float* __restrict__ out)
{
    __shared__ uint4  sWin[R0R * R0C];          // 5.8 KB
    __shared__ float2 sIS [R0R * R0C];          // 2.9 KB
    __shared__ float  sR0 [R0R * R0C];          // 1.4 KB
    __shared__ float  sR1 [R1R * R1C];          // 1.3 KB
    __shared__ float  sR2 [R2R * R2C];          // 1.2 KB

    const int tid = threadIdx.x;
    const int h0 = blockIdx.x * HT;
    const int w0 = blockIdx.y * WT;
    const int s  = blockIdx.z;

    // phase 0: stage window + (imin,sc); eval round 0 (horizontal) in regs
    for (int i = tid; i < R0R * R0C; i += 256) {
        const int r = i / R0C, c = i - R0C * r;
        const int gh = h0 - 2 + r, gw = w0 - 1 + c;
        float dn = 0.0f, imin = 0.0f, sc = 0.0f;
        uint4 wb = make_uint4(0, 0, 0, 0);
        if ((unsigned)gh < (unsigned)H && (unsigned)gw < (unsigned)W) {
            const int g = gh * W + gw;
            wb = wbuf[s * HW + g];
            const float mind = fmaxf(min_disp[g], 0.0f);
            const float maxd = fmaxf(max_disp[g], 0.0f);
            sc = (maxd - mind) * INTERVAL;
            imin = fmaf(sc, (float)(s + 1), mind);
            const int kb0 = win_base(imin, sc);
            float np[3];
            #pragma unroll
            for (int t = 0; t < 3; ++t) {
                const int x = gw + t - 1;
                np[t] = ((unsigned)x < (unsigned)W) ? noise[s * HW + gh * W + x] : 0.0f;
            }
            float ds;
            eval_w(wb.x, wb.y, wb.z, wb.w, kb0, gw, imin, sc, np, ds, dn);
        }
        sWin[i] = wb;
        sIS[i]  = make_float2(imin, sc);
        sR0[i]  = dn;
    }
    __syncthreads();

    // phase 1: round 1 (vertical), np from sR0
    for (int i = tid; i < R1R * R1C; i += 256) {
        const int r = i / R1C, c = i - R1C * r;
        const int gh = h0 - 1 + r, gw = w0 - 1 + c;
        float dn = 0.0f;
        if ((unsigned)gh < (unsigned)H && (unsigned)gw < (unsigned)W) {
            const int p0 = (r + 1) * R0C + c;
            const uint4 wb = sWin[p0];
            const float2 is = sIS[p0];
            const int kb0 = win_base(is.x, is.y);
            float np[3];
            #pragma unroll
            for (int t = 0; t < 3; ++t) np[t] = sR0[(r + t) * R0C + c];
            float ds;
            eval_w(wb.x, wb.y, wb.z, wb.w, kb0, gw, is.x, is.y, np, ds, dn);
        }
        sR1[i] = dn;
    }
    __syncthreads();

    // phase 2: round 2 (horizontal), np from sR1
    for (int i = tid; i < R2R * R2C; i += 256) {
        const int r = i >> 4, c = i & 15;
        const int gh = h0 - 1 + r, gw = w0 + c;
        float dn = 0.0f;
        if ((unsigned)gh < (unsigned)H) {       // gw always in [0,W)
            const int p0 = (r + 1) * R0C + (c + 1);
            const uint4 wb = sWin[p0];
            const float2 is = sIS[p0];
            const int kb0 = win_base(is.x, is.y);
            float np[3];
            #pragma unroll
            for (int t = 0; t < 3; ++t) np[t] = sR1[r * R1C + (c + t)];
            float ds;
            eval_w(wb.x, wb.y, wb.z, wb.w, kb0, gw, is.x, is.y, np, ds, dn);
        }
        sR2[i] = dn;
    }
    __syncthreads();

    // phase 3: round 3 (vertical), np from sR2 -> ds -> out
    for (int i = tid; i < HT * WT; i += 256) {
        const int r = i >> 4, c = i & 15;
        const int gh = h0 + r, gw = w0 + c;
        const int p0 = (r + 2) * R0C + (c + 1);
        const uint4 wb = sWin[p0];
        const float2 is = sIS[p0];
        const int kb0 = win_base(is.x, is.y);
        float np[3];
        #pragma unroll
        for (int t = 0; t < 3; ++t) np[t] = sR2[(r + t) * R2C + c];
        float ds, dn;
        eval_w(wb.x, wb.y, wb.z, wb.w, kb0, gw, is.x, is.y, np, ds, dn);
        out[s * HW + gh * W + gw] = ds;
    }
}

extern "C" void kernel_launch(void* const* d_in, const int* in_sizes, int n_in,
                              void* d_out, int out_size, void* d_ws, size_t ws_size,
                              hipStream_t stream) {
    const float* left  = (const float*)d_in[0];
    const float* right = (const float*)d_in[1];
    const float* mind  = (const float*)d_in[2];
    const float* maxd  = (const float*)d_in[3];
    const float* noise = (const float*)d_in[4];
    float* out  = (float*)d_out;
    uint4* wbuf = (uint4*)d_ws;                    // S*H*W uint4 = 6.3 MB

    dim3 block(256);
    pm_build<<<dim3(H, 4), block, 0, stream>>>(left, right, mind, maxd, wbuf);
    pm_prop<<<dim3(H / HT, W / WT, S), block, 0, stream>>>(mind, maxd, wbuf,
                                                           noise, out);
}